// Round 2
// baseline (592.362 us; speedup 1.0000x reference)
//
#include <hip/hip_runtime.h>
#include <hip/hip_bf16.h>

#define H_DIM 1024
#define NE 8
#define IDIM 1408
#define SIDIM 2816
#define NTOK 2048

typedef __attribute__((ext_vector_type(8))) _Float16 half8;
typedef __attribute__((ext_vector_type(4))) float f32x4;

// async global->LDS, 16B per lane. LDS dest = wave-uniform base + lane*16.
__device__ __forceinline__ void gload_lds16(const void* g, void* l) {
    __builtin_amdgcn_global_load_lds(
        (const __attribute__((address_space(1))) void*)g,
        (__attribute__((address_space(3))) void*)l, 16, 0, 0);
}

// Stage ROWS x 64 f16 tile (row stride = `stride` elems) into linear LDS.
// 1KB chunk = 8 rows; lane l covers row (l>>3), col (l&7)*8 of its chunk.
template <int ROWS>
__device__ __forceinline__ void stage_rows(const _Float16* __restrict__ src,
                                           size_t stride, _Float16* lds, int tid) {
    const int w = tid >> 6, l = tid & 63;
    const int r8 = l >> 3, c8 = (l & 7) * 8;
#pragma unroll
    for (int c = 0; c < ROWS / 8; c += 4) {
        const int ch = c + w;
        gload_lds16(src + (size_t)(ch * 8 + r8) * stride + c8, lds + ch * 512);
    }
}

// ---------------------------------------------------------------- convert (all 6 buffers, one launch)
__global__ __launch_bounds__(256) void cvt_all_kernel(
    const float* __restrict__ x, const float* __restrict__ gu,
    const float* __restrict__ down, const float* __restrict__ sg,
    const float* __restrict__ su, const float* __restrict__ sd,
    _Float16* __restrict__ xb, _Float16* __restrict__ gub,
    _Float16* __restrict__ downb, _Float16* __restrict__ sgb,
    _Float16* __restrict__ sub, _Float16* __restrict__ sdb) {
    int b = blockIdx.x;
    const float* s; _Float16* d; int off;
    if (b < 1024)       { s = x;    d = xb;    off = b; }
    else if (b < 12288) { s = gu;   d = gub;   off = b - 1024; }
    else if (b < 17920) { s = down; d = downb; off = b - 12288; }
    else if (b < 19328) { s = sg;   d = sgb;   off = b - 17920; }
    else if (b < 20736) { s = su;   d = sub;   off = b - 19328; }
    else                { s = sd;   d = sdb;   off = b - 20736; }
    size_t i = ((size_t)off * 256 + threadIdx.x) * 8;
    float4 a = *(const float4*)(s + i);
    float4 c = *(const float4*)(s + i + 4);
    half8 o;
    o[0] = (_Float16)a.x; o[1] = (_Float16)a.y; o[2] = (_Float16)a.z; o[3] = (_Float16)a.w;
    o[4] = (_Float16)c.x; o[5] = (_Float16)c.y; o[6] = (_Float16)c.z; o[7] = (_Float16)c.w;
    *(half8*)(d + i) = o;
}

// ---------------------------------------------------------------- router
__global__ __launch_bounds__(256) void router_kernel(
    const float* __restrict__ x, const float* __restrict__ gate_w,
    const float* __restrict__ seg_w, float* __restrict__ wbuf,
    float* __restrict__ swbuf) {
    const int wave = threadIdx.x >> 6, lane = threadIdx.x & 63;
    const int n = blockIdx.x * 4 + wave;
    const float* xr = x + (size_t)n * H_DIM;
    float4 xv[4];
#pragma unroll
    for (int i = 0; i < 4; ++i) xv[i] = *(const float4*)(xr + i * 256 + lane * 4);
    float logits[9];
    for (int e = 0; e < 9; ++e) {
        const float* wr = (e < 8) ? (gate_w + (size_t)e * H_DIM) : seg_w;
        float p = 0.f;
#pragma unroll
        for (int i = 0; i < 4; ++i) {
            float4 wv = *(const float4*)(wr + i * 256 + lane * 4);
            p += xv[i].x * wv.x + xv[i].y * wv.y + xv[i].z * wv.z + xv[i].w * wv.w;
        }
#pragma unroll
        for (int m = 32; m > 0; m >>= 1) p += __shfl_xor(p, m, 64);
        logits[e] = p;
    }
    float mx = logits[0];
#pragma unroll
    for (int e = 1; e < 8; ++e) mx = fmaxf(mx, logits[e]);
    float pe[8], s = 0.f;
#pragma unroll
    for (int e = 0; e < 8; ++e) { pe[e] = expf(logits[e] - mx); s += pe[e]; }
    int i1 = 0;
#pragma unroll
    for (int e = 1; e < 8; ++e) if (logits[e] > logits[i1]) i1 = e;
    int i2 = -1;
#pragma unroll
    for (int e = 0; e < 8; ++e) {
        if (e == i1) continue;
        if (i2 < 0 || logits[e] > logits[i2]) i2 = e;
    }
    if (lane < 8) wbuf[n * NE + lane] = (lane == i1 || lane == i2) ? pe[lane] / s : 0.f;
    if (lane == 8) swbuf[n] = 1.f / (1.f + expf(-logits[8]));
}

// ---------------------------------------------------------------- per-expert token lists
__global__ __launch_bounds__(512) void build_lists_kernel(
    const float* __restrict__ wbuf, int* __restrict__ list, int* __restrict__ cnt) {
    const int e = threadIdx.x >> 6, lane = threadIdx.x & 63;
    int base = 0;
    for (int n0 = 0; n0 < NTOK; n0 += 64) {
        float v = wbuf[(size_t)(n0 + lane) * NE + e];
        unsigned long long m = __ballot(v > 0.f);
        int pre = __popcll(m & ((1ull << lane) - 1ull));
        if (v > 0.f) list[e * NTOK + base + pre] = n0 + lane;
        base += __popcll(m);
    }
    if (lane == 0) cnt[e] = base;
}

// ---------------------------------------------------------------- GEMM1 (gate+up fused, silu, scale -> f16 h)
// BM=128 tokens x BN=64 I-cols (dual B panels), BK=64. 4 waves 2x2, wave = 64x32(g)+64x32(u).
template <int MODE>
__global__ __launch_bounds__(256) void gemm1_kernel(
    const _Float16* __restrict__ xb, const _Float16* __restrict__ Bg0,
    const _Float16* __restrict__ Bu0, const float* __restrict__ scale,
    const int* __restrict__ list, const int* __restrict__ cnt,
    _Float16* __restrict__ hout) {
    const int e = blockIdx.z;
    const int m0 = blockIdx.x * 128;   // m fastest: consecutive blocks share weight panel
    const int n0 = blockIdx.y * 64;
    int count;
    const _Float16 *Bg, *Bu;
    _Float16* out;
    int outStride;
    if (MODE == 0) {
        count = cnt[e];
        if (m0 >= count) return;
        Bg = Bg0 + (size_t)e * (2 * IDIM * H_DIM) + (size_t)n0 * H_DIM;
        Bu = Bg + (size_t)IDIM * H_DIM;
        out = hout + (size_t)e * NTOK * IDIM;
        outStride = IDIM;
    } else {
        count = NTOK;
        Bg = Bg0 + (size_t)n0 * H_DIM;
        Bu = Bu0 + (size_t)n0 * H_DIM;
        out = hout;
        outStride = SIDIM;
    }
    __shared__ __align__(16) _Float16 As[128 * 64];
    __shared__ __align__(16) _Float16 Bgs[64 * 64];
    __shared__ __align__(16) _Float16 Bus[64 * 64];
    __shared__ int toks[128];
    const int tid = threadIdx.x;
    if (tid < 128) {
        int slot = m0 + tid;
        toks[tid] = (MODE == 0) ? list[e * NTOK + (slot < count ? slot : count - 1)] : slot;
    }
    __syncthreads();
    const int lane = tid & 63, wv = tid >> 6;
    const int wr = wv >> 1, wc = wv & 1;
    const int fr = lane & 15, fk = (lane >> 4) * 8;
    // hoist per-lane A gather addresses (4 chunks per thread)
    const int r8 = lane >> 3, c8 = (lane & 7) * 8;
    const _Float16* aptr[4];
#pragma unroll
    for (int c = 0; c < 4; ++c)
        aptr[c] = xb + (size_t)toks[(c * 4 + wv) * 8 + r8] * H_DIM + c8;
    f32x4 accg[4][2] = {};
    f32x4 accu[4][2] = {};
    for (int k0 = 0; k0 < H_DIM; k0 += 64) {
#pragma unroll
        for (int c = 0; c < 4; ++c)
            gload_lds16(aptr[c] + k0, As + (c * 4 + wv) * 512);
        stage_rows<64>(Bg + k0, H_DIM, Bgs, tid);
        stage_rows<64>(Bu + k0, H_DIM, Bus, tid);
        __syncthreads();
#pragma unroll
        for (int kk = 0; kk < 2; ++kk) {
            half8 af[4], bgf[2], buf2[2];
#pragma unroll
            for (int mi = 0; mi < 4; ++mi)
                af[mi] = *(const half8*)&As[(wr * 64 + mi * 16 + fr) * 64 + kk * 32 + fk];
#pragma unroll
            for (int ni = 0; ni < 2; ++ni) {
                bgf[ni] = *(const half8*)&Bgs[(wc * 32 + ni * 16 + fr) * 64 + kk * 32 + fk];
                buf2[ni] = *(const half8*)&Bus[(wc * 32 + ni * 16 + fr) * 64 + kk * 32 + fk];
            }
#pragma unroll
            for (int mi = 0; mi < 4; ++mi)
#pragma unroll
                for (int ni = 0; ni < 2; ++ni) {
                    accg[mi][ni] = __builtin_amdgcn_mfma_f32_16x16x32_f16(af[mi], bgf[ni],
                                                                          accg[mi][ni], 0, 0, 0);
                    accu[mi][ni] = __builtin_amdgcn_mfma_f32_16x16x32_f16(af[mi], buf2[ni],
                                                                          accu[mi][ni], 0, 0, 0);
                }
        }
        __syncthreads();
    }
    const int j4 = (lane >> 4) * 4;
#pragma unroll
    for (int mi = 0; mi < 4; ++mi) {
#pragma unroll
        for (int j = 0; j < 4; ++j) {
            int r = wr * 64 + mi * 16 + j4 + j;
            int slot = m0 + r;
            float sc;
            if (MODE == 0)
                sc = (slot < count) ? scale[(size_t)toks[r] * NE + e] : 0.f;
            else
                sc = scale[slot];
#pragma unroll
            for (int ni = 0; ni < 2; ++ni) {
                float g = accg[mi][ni][j];
                float u = accu[mi][ni][j];
                float hv = sc * (g / (1.f + expf(-g))) * u;
                out[(size_t)slot * outStride + n0 + wc * 32 + ni * 16 + fr] = (_Float16)hv;
            }
        }
    }
}

// ---------------------------------------------------------------- GEMM2 (128x128 tile, 4 waves 2x2)
// MODE 0: sparse MoE (A=hm[e] slots, B=down_b[e], atomic scatter-add via list)
// MODE 1: dense shared (A=hs, B=sd_b, plain store — initializes out)
template <int MODE>
__global__ __launch_bounds__(256) void gemm2_kernel(
    const _Float16* __restrict__ A0, const _Float16* __restrict__ B0,
    const int* __restrict__ list, const int* __restrict__ cnt,
    float* __restrict__ out) {
    const int e = blockIdx.z;
    const int m0 = blockIdx.x * 128;
    const int n0 = blockIdx.y * 128;
    constexpr int K = (MODE == 0) ? IDIM : SIDIM;
    const int count = (MODE == 0) ? cnt[e] : NTOK;
    if (MODE == 0 && m0 >= count) return;
    const _Float16* A = (MODE == 0)
        ? A0 + (size_t)e * NTOK * IDIM + (size_t)m0 * K
        : A0 + (size_t)m0 * K;
    const _Float16* B = (MODE == 0)
        ? B0 + (size_t)e * H_DIM * IDIM + (size_t)n0 * K
        : B0 + (size_t)n0 * K;
    __shared__ __align__(16) _Float16 As[128 * 64];
    __shared__ __align__(16) _Float16 Bs[128 * 64];
    const int tid = threadIdx.x;
    const int lane = tid & 63, wv = tid >> 6;
    const int wr = wv >> 1, wc = wv & 1;
    const int fr = lane & 15, fk = (lane >> 4) * 8;
    f32x4 acc[4][4] = {};
    for (int k0 = 0; k0 < K; k0 += 64) {
        stage_rows<128>(A + k0, K, As, tid);
        stage_rows<128>(B + k0, K, Bs, tid);
        __syncthreads();
#pragma unroll
        for (int kk = 0; kk < 2; ++kk) {
            half8 af[4], bf[4];
#pragma unroll
            for (int mi = 0; mi < 4; ++mi)
                af[mi] = *(const half8*)&As[(wr * 64 + mi * 16 + fr) * 64 + kk * 32 + fk];
#pragma unroll
            for (int ni = 0; ni < 4; ++ni)
                bf[ni] = *(const half8*)&Bs[(wc * 64 + ni * 16 + fr) * 64 + kk * 32 + fk];
#pragma unroll
            for (int mi = 0; mi < 4; ++mi)
#pragma unroll
                for (int ni = 0; ni < 4; ++ni)
                    acc[mi][ni] = __builtin_amdgcn_mfma_f32_16x16x32_f16(af[mi], bf[ni],
                                                                         acc[mi][ni], 0, 0, 0);
        }
        __syncthreads();
    }
    const int j4 = (lane >> 4) * 4;
#pragma unroll
    for (int mi = 0; mi < 4; ++mi)
#pragma unroll
        for (int j = 0; j < 4; ++j) {
            int r = wr * 64 + mi * 16 + j4 + j;
            int slot = m0 + r;
            if (MODE == 0) {
                if (slot < count) {
                    int tok = list[e * NTOK + slot];
#pragma unroll
                    for (int ni = 0; ni < 4; ++ni)
                        atomicAdd(&out[(size_t)tok * H_DIM + n0 + wc * 64 + ni * 16 + fr],
                                  acc[mi][ni][j]);
                }
            } else {
#pragma unroll
                for (int ni = 0; ni < 4; ++ni)
                    out[(size_t)slot * H_DIM + n0 + wc * 64 + ni * 16 + fr] = acc[mi][ni][j];
            }
        }
}

// ---------------------------------------------------------------- launch
extern "C" void kernel_launch(void* const* d_in, const int* in_sizes, int n_in,
                              void* d_out, int out_size, void* d_ws, size_t ws_size,
                              hipStream_t stream) {
    const float* x = (const float*)d_in[0];
    const float* gate_w = (const float*)d_in[1];
    const float* egu = (const float*)d_in[2];
    const float* edown = (const float*)d_in[3];
    const float* sgw = (const float*)d_in[4];
    const float* suw = (const float*)d_in[5];
    const float* sdw = (const float*)d_in[6];
    const float* segw = (const float*)d_in[7];
    float* out = (float*)d_out;

    _Float16* xb = (_Float16*)d_ws;
    _Float16* gu_b = xb + (size_t)NTOK * H_DIM;
    _Float16* down_b = gu_b + (size_t)NE * 2 * IDIM * H_DIM;
    _Float16* sg_b = down_b + (size_t)NE * H_DIM * IDIM;
    _Float16* su_b = sg_b + (size_t)SIDIM * H_DIM;
    _Float16* sd_b = su_b + (size_t)SIDIM * H_DIM;
    _Float16* hm = sd_b + (size_t)H_DIM * SIDIM;
    _Float16* hs = hm + (size_t)NE * NTOK * IDIM;
    float* wbuf = (float*)(hs + (size_t)NTOK * SIDIM);
    float* swbuf = wbuf + NTOK * NE;
    int* cnt = (int*)(swbuf + NTOK);
    int* list = cnt + NE;

    dim3 blk(256);
    cvt_all_kernel<<<22144, blk, 0, stream>>>(x, egu, edown, sgw, suw, sdw,
                                              xb, gu_b, down_b, sg_b, su_b, sd_b);
    router_kernel<<<NTOK / 4, blk, 0, stream>>>(x, gate_w, segw, wbuf, swbuf);
    build_lists_kernel<<<1, 512, 0, stream>>>(wbuf, list, cnt);
    gemm1_kernel<0><<<dim3(NTOK / 128, IDIM / 64, NE), blk, 0, stream>>>(
        xb, gu_b, nullptr, wbuf, list, cnt, hm);
    gemm1_kernel<1><<<dim3(NTOK / 128, SIDIM / 64, 1), blk, 0, stream>>>(
        xb, sg_b, su_b, swbuf, list, cnt, hs);
    gemm2_kernel<1><<<dim3(NTOK / 128, H_DIM / 128, 1), blk, 0, stream>>>(
        hs, sd_b, list, cnt, out);
    gemm2_kernel<0><<<dim3(NTOK / 128, H_DIM / 128, NE), blk, 0, stream>>>(
        hm, down_b, list, cnt, out);
    (void)in_sizes; (void)n_in; (void)out_size; (void)ws_size;
}

// Round 3
// 463.992 us; speedup vs baseline: 1.2767x; 1.2767x over previous
//
#include <hip/hip_runtime.h>
#include <hip/hip_bf16.h>

#define H_DIM 1024
#define NE 8
#define IDIM 1408
#define SIDIM 2816
#define NTOK 2048

typedef __attribute__((ext_vector_type(8))) _Float16 half8;
typedef __attribute__((ext_vector_type(4))) float f32x4;

// async global->LDS, 16B per lane. LDS dest = wave-uniform base + lane*16.
__device__ __forceinline__ void gload_lds16(const void* g, void* l) {
    __builtin_amdgcn_global_load_lds(
        (const __attribute__((address_space(1))) void*)g,
        (__attribute__((address_space(3))) void*)l, 16, 0, 0);
}

// ---------------------------------------------------------------- convert (all 6 buffers, one launch)
__global__ __launch_bounds__(256) void cvt_all_kernel(
    const float* __restrict__ x, const float* __restrict__ gu,
    const float* __restrict__ down, const float* __restrict__ sg,
    const float* __restrict__ su, const float* __restrict__ sd,
    _Float16* __restrict__ xb, _Float16* __restrict__ gub,
    _Float16* __restrict__ downb, _Float16* __restrict__ sgb,
    _Float16* __restrict__ sub, _Float16* __restrict__ sdb) {
    int b = blockIdx.x;
    const float* s; _Float16* d; int off;
    if (b < 1024)       { s = x;    d = xb;    off = b; }
    else if (b < 12288) { s = gu;   d = gub;   off = b - 1024; }
    else if (b < 17920) { s = down; d = downb; off = b - 12288; }
    else if (b < 19328) { s = sg;   d = sgb;   off = b - 17920; }
    else if (b < 20736) { s = su;   d = sub;   off = b - 19328; }
    else                { s = sd;   d = sdb;   off = b - 20736; }
    size_t i = ((size_t)off * 256 + threadIdx.x) * 8;
    float4 a = *(const float4*)(s + i);
    float4 c = *(const float4*)(s + i + 4);
    half8 o;
    o[0] = (_Float16)a.x; o[1] = (_Float16)a.y; o[2] = (_Float16)a.z; o[3] = (_Float16)a.w;
    o[4] = (_Float16)c.x; o[5] = (_Float16)c.y; o[6] = (_Float16)c.z; o[7] = (_Float16)c.w;
    *(half8*)(d + i) = o;
}

// ---------------------------------------------------------------- router
__global__ __launch_bounds__(256) void router_kernel(
    const float* __restrict__ x, const float* __restrict__ gate_w,
    const float* __restrict__ seg_w, float* __restrict__ wbuf,
    float* __restrict__ swbuf) {
    const int wave = threadIdx.x >> 6, lane = threadIdx.x & 63;
    const int n = blockIdx.x * 4 + wave;
    const float* xr = x + (size_t)n * H_DIM;
    float4 xv[4];
#pragma unroll
    for (int i = 0; i < 4; ++i) xv[i] = *(const float4*)(xr + i * 256 + lane * 4);
    float logits[9];
    for (int e = 0; e < 9; ++e) {
        const float* wr = (e < 8) ? (gate_w + (size_t)e * H_DIM) : seg_w;
        float p = 0.f;
#pragma unroll
        for (int i = 0; i < 4; ++i) {
            float4 wv = *(const float4*)(wr + i * 256 + lane * 4);
            p += xv[i].x * wv.x + xv[i].y * wv.y + xv[i].z * wv.z + xv[i].w * wv.w;
        }
#pragma unroll
        for (int m = 32; m > 0; m >>= 1) p += __shfl_xor(p, m, 64);
        logits[e] = p;
    }
    float mx = logits[0];
#pragma unroll
    for (int e = 1; e < 8; ++e) mx = fmaxf(mx, logits[e]);
    float pe[8], s = 0.f;
#pragma unroll
    for (int e = 0; e < 8; ++e) { pe[e] = expf(logits[e] - mx); s += pe[e]; }
    int i1 = 0;
#pragma unroll
    for (int e = 1; e < 8; ++e) if (logits[e] > logits[i1]) i1 = e;
    int i2 = -1;
#pragma unroll
    for (int e = 0; e < 8; ++e) {
        if (e == i1) continue;
        if (i2 < 0 || logits[e] > logits[i2]) i2 = e;
    }
    if (lane < 8) wbuf[n * NE + lane] = (lane == i1 || lane == i2) ? pe[lane] / s : 0.f;
    if (lane == 8) swbuf[n] = 1.f / (1.f + expf(-logits[8]));
}

// ---------------------------------------------------------------- lists + compacted tile tables
// t128[i] = (e<<16)|mtile for 128-row tiles (gemm1), t64 for 64-row tiles (gemm2).
// totals: cnt[8] = n128, cnt[9] = n64.
__global__ __launch_bounds__(512) void build_lists_kernel(
    const float* __restrict__ wbuf, int* __restrict__ list, int* __restrict__ cnt,
    int* __restrict__ t128, int* __restrict__ t64) {
    const int e = threadIdx.x >> 6, lane = threadIdx.x & 63;
    int base = 0;
    for (int n0 = 0; n0 < NTOK; n0 += 64) {
        float v = wbuf[(size_t)(n0 + lane) * NE + e];
        unsigned long long m = __ballot(v > 0.f);
        int pre = __popcll(m & ((1ull << lane) - 1ull));
        if (v > 0.f) list[e * NTOK + base + pre] = n0 + lane;
        base += __popcll(m);
    }
    if (lane == 0) cnt[e] = base;
    __syncthreads();
    if (threadIdx.x == 0) {
        int n128 = 0, n64 = 0;
        for (int ee = 0; ee < NE; ++ee) {
            int c = cnt[ee];
            for (int m = 0; m < c; m += 128) t128[n128++] = (ee << 16) | (m >> 7);
            for (int m = 0; m < c; m += 64)  t64[n64++]  = (ee << 16) | (m >> 6);
        }
        cnt[8] = n128; cnt[9] = n64;
    }
}

// ---------------------------------------------------------------- GEMM1 (gate+up fused, silu, scale -> f16 h)
// BM=128 x BN=64 (dual B panels g,u), BK=64, 2-phase dbuf gload_lds. 4 waves 2x2.
template <int MODE>
__global__ __launch_bounds__(256) void gemm1_kernel(
    const _Float16* __restrict__ xb, const _Float16* __restrict__ Bg0,
    const _Float16* __restrict__ Bu0, const float* __restrict__ scale,
    const int* __restrict__ list, const int* __restrict__ cnt,
    const int* __restrict__ t128, _Float16* __restrict__ hout) {
    int e, m0, count;
    if (MODE == 0) {
        if ((int)blockIdx.x >= cnt[8]) return;
        int pk = t128[blockIdx.x];
        e = pk >> 16; m0 = (pk & 0xffff) << 7; count = cnt[e];
    } else {
        e = 0; m0 = blockIdx.x << 7; count = NTOK;
    }
    const int n0 = blockIdx.y * 64;
    const _Float16 *Bg, *Bu; _Float16* out; int outStride;
    if (MODE == 0) {
        Bg = Bg0 + (size_t)e * (2 * IDIM * H_DIM) + (size_t)n0 * H_DIM;
        Bu = Bg + (size_t)IDIM * H_DIM;
        out = hout + (size_t)e * NTOK * IDIM; outStride = IDIM;
    } else {
        Bg = Bg0 + (size_t)n0 * H_DIM;
        Bu = Bu0 + (size_t)n0 * H_DIM;
        out = hout; outStride = SIDIM;
    }
    __shared__ __align__(16) _Float16 As[2][128 * 64];
    __shared__ __align__(16) _Float16 Bgs[2][64 * 64];
    __shared__ __align__(16) _Float16 Bus[2][64 * 64];
    __shared__ int toks[128];
    const int tid = threadIdx.x;
    if (tid < 128) {
        int slot = m0 + tid;
        toks[tid] = (MODE == 0) ? list[e * NTOK + (slot < count ? slot : count - 1)] : slot;
    }
    __syncthreads();
    const int lane = tid & 63, wv = tid >> 6;
    const int wr = wv >> 1, wc = wv & 1;
    const int fr = lane & 15, fk = (lane >> 4) * 8;
    const int r8 = lane >> 3, c8 = (lane & 7) * 8;
    const _Float16 *ap[4], *gp[2], *up[2];
#pragma unroll
    for (int c = 0; c < 4; ++c)
        ap[c] = xb + (size_t)toks[(c * 4 + wv) * 8 + r8] * H_DIM + c8;
#pragma unroll
    for (int c = 0; c < 2; ++c) {
        gp[c] = Bg + (size_t)((c * 4 + wv) * 8 + r8) * H_DIM + c8;
        up[c] = Bu + (size_t)((c * 4 + wv) * 8 + r8) * H_DIM + c8;
    }
    f32x4 accg[4][2] = {};
    f32x4 accu[4][2] = {};

    auto STAGE = [&](int buf, int k0) {
#pragma unroll
        for (int c = 0; c < 4; ++c)
            gload_lds16(ap[c] + k0, &As[buf][(c * 4 + wv) * 512]);
#pragma unroll
        for (int c = 0; c < 2; ++c) {
            gload_lds16(gp[c] + k0, &Bgs[buf][(c * 4 + wv) * 512]);
            gload_lds16(up[c] + k0, &Bus[buf][(c * 4 + wv) * 512]);
        }
    };
    auto COMPUTE = [&](int buf) {
#pragma unroll
        for (int kk = 0; kk < 2; ++kk) {
            half8 af[4], bgf[2], buf2[2];
#pragma unroll
            for (int mi = 0; mi < 4; ++mi)
                af[mi] = *(const half8*)&As[buf][(wr * 64 + mi * 16 + fr) * 64 + kk * 32 + fk];
#pragma unroll
            for (int ni = 0; ni < 2; ++ni) {
                bgf[ni] = *(const half8*)&Bgs[buf][(wc * 32 + ni * 16 + fr) * 64 + kk * 32 + fk];
                buf2[ni] = *(const half8*)&Bus[buf][(wc * 32 + ni * 16 + fr) * 64 + kk * 32 + fk];
            }
#pragma unroll
            for (int mi = 0; mi < 4; ++mi)
#pragma unroll
                for (int ni = 0; ni < 2; ++ni) {
                    accg[mi][ni] = __builtin_amdgcn_mfma_f32_16x16x32_f16(af[mi], bgf[ni],
                                                                          accg[mi][ni], 0, 0, 0);
                    accu[mi][ni] = __builtin_amdgcn_mfma_f32_16x16x32_f16(af[mi], buf2[ni],
                                                                          accu[mi][ni], 0, 0, 0);
                }
        }
    };

    constexpr int NKT = H_DIM / 64;
    STAGE(0, 0);
    __syncthreads();                 // drains vmcnt(0): buf0 ready
    for (int t = 0; t < NKT - 1; ++t) {
        const int cur = t & 1;
        STAGE(cur ^ 1, (t + 1) * 64);   // prefetch next tile (latency hides under MFMA)
        COMPUTE(cur);
        __syncthreads();                // waits vmcnt(0): next buf ready; readers done
    }
    COMPUTE((NKT - 1) & 1);

    const int j4 = (lane >> 4) * 4;
#pragma unroll
    for (int mi = 0; mi < 4; ++mi) {
#pragma unroll
        for (int j = 0; j < 4; ++j) {
            int r = wr * 64 + mi * 16 + j4 + j;
            int slot = m0 + r;
            float sc;
            if (MODE == 0)
                sc = (slot < count) ? scale[(size_t)toks[r] * NE + e] : 0.f;
            else
                sc = scale[slot];
#pragma unroll
            for (int ni = 0; ni < 2; ++ni) {
                float g = accg[mi][ni][j];
                float u = accu[mi][ni][j];
                float hv = sc * (g / (1.f + expf(-g))) * u;
                out[(size_t)slot * outStride + n0 + wc * 32 + ni * 16 + fr] = (_Float16)hv;
            }
        }
    }
}

// ---------------------------------------------------------------- GEMM2 (BM=64 x BN=128, BK=64, dbuf)
// MODE 0: sparse MoE via t64 table, atomic scatter-add. MODE 1: dense shared, plain store.
template <int MODE>
__global__ __launch_bounds__(256) void gemm2_kernel(
    const _Float16* __restrict__ A0, const _Float16* __restrict__ B0,
    const int* __restrict__ list, const int* __restrict__ cnt,
    const int* __restrict__ t64, float* __restrict__ out) {
    constexpr int K = (MODE == 0) ? IDIM : SIDIM;
    int e, m0, count;
    if (MODE == 0) {
        if ((int)blockIdx.x >= cnt[9]) return;
        int pk = t64[blockIdx.x];
        e = pk >> 16; m0 = (pk & 0xffff) << 6; count = cnt[e];
    } else {
        e = 0; m0 = blockIdx.x << 6; count = NTOK;
    }
    const int n0 = blockIdx.y * 128;
    const _Float16* A = (MODE == 0)
        ? A0 + (size_t)e * NTOK * IDIM + (size_t)m0 * K
        : A0 + (size_t)m0 * K;
    const _Float16* B = (MODE == 0)
        ? B0 + (size_t)e * H_DIM * IDIM + (size_t)n0 * K
        : B0 + (size_t)n0 * K;
    __shared__ __align__(16) _Float16 As[2][64 * 64];
    __shared__ __align__(16) _Float16 Bs[2][128 * 64];
    const int tid = threadIdx.x;
    const int lane = tid & 63, wv = tid >> 6;
    const int wr = wv >> 1, wc = wv & 1;
    const int fr = lane & 15, fk = (lane >> 4) * 8;
    const int r8 = lane >> 3, c8 = (lane & 7) * 8;
    const _Float16 *apr[2], *bpr[4];
#pragma unroll
    for (int c = 0; c < 2; ++c)
        apr[c] = A + (size_t)((c * 4 + wv) * 8 + r8) * K + c8;
#pragma unroll
    for (int c = 0; c < 4; ++c)
        bpr[c] = B + (size_t)((c * 4 + wv) * 8 + r8) * K + c8;
    f32x4 acc[2][4] = {};

    auto STAGE = [&](int buf, int k0) {
#pragma unroll
        for (int c = 0; c < 2; ++c)
            gload_lds16(apr[c] + k0, &As[buf][(c * 4 + wv) * 512]);
#pragma unroll
        for (int c = 0; c < 4; ++c)
            gload_lds16(bpr[c] + k0, &Bs[buf][(c * 4 + wv) * 512]);
    };
    auto COMPUTE = [&](int buf) {
#pragma unroll
        for (int kk = 0; kk < 2; ++kk) {
            half8 af[2], bf[4];
#pragma unroll
            for (int mi = 0; mi < 2; ++mi)
                af[mi] = *(const half8*)&As[buf][(wr * 32 + mi * 16 + fr) * 64 + kk * 32 + fk];
#pragma unroll
            for (int ni = 0; ni < 4; ++ni)
                bf[ni] = *(const half8*)&Bs[buf][(wc * 64 + ni * 16 + fr) * 64 + kk * 32 + fk];
#pragma unroll
            for (int mi = 0; mi < 2; ++mi)
#pragma unroll
                for (int ni = 0; ni < 4; ++ni)
                    acc[mi][ni] = __builtin_amdgcn_mfma_f32_16x16x32_f16(af[mi], bf[ni],
                                                                         acc[mi][ni], 0, 0, 0);
        }
    };

    constexpr int NKT = K / 64;
    STAGE(0, 0);
    __syncthreads();
    for (int t = 0; t < NKT - 1; ++t) {
        const int cur = t & 1;
        STAGE(cur ^ 1, (t + 1) * 64);
        COMPUTE(cur);
        __syncthreads();
    }
    COMPUTE((NKT - 1) & 1);

    const int j4 = (lane >> 4) * 4;
#pragma unroll
    for (int mi = 0; mi < 2; ++mi)
#pragma unroll
        for (int j = 0; j < 4; ++j) {
            int r = wr * 32 + mi * 16 + j4 + j;
            int slot = m0 + r;
            if (MODE == 0) {
                if (slot < count) {
                    int tok = list[e * NTOK + slot];
#pragma unroll
                    for (int ni = 0; ni < 4; ++ni)
                        atomicAdd(&out[(size_t)tok * H_DIM + n0 + wc * 64 + ni * 16 + fr],
                                  acc[mi][ni][j]);
                }
            } else {
#pragma unroll
                for (int ni = 0; ni < 4; ++ni)
                    out[(size_t)slot * H_DIM + n0 + wc * 64 + ni * 16 + fr] = acc[mi][ni][j];
            }
        }
}

// ---------------------------------------------------------------- launch
extern "C" void kernel_launch(void* const* d_in, const int* in_sizes, int n_in,
                              void* d_out, int out_size, void* d_ws, size_t ws_size,
                              hipStream_t stream) {
    const float* x = (const float*)d_in[0];
    const float* gate_w = (const float*)d_in[1];
    const float* egu = (const float*)d_in[2];
    const float* edown = (const float*)d_in[3];
    const float* sgw = (const float*)d_in[4];
    const float* suw = (const float*)d_in[5];
    const float* sdw = (const float*)d_in[6];
    const float* segw = (const float*)d_in[7];
    float* out = (float*)d_out;

    _Float16* xb = (_Float16*)d_ws;
    _Float16* gu_b = xb + (size_t)NTOK * H_DIM;
    _Float16* down_b = gu_b + (size_t)NE * 2 * IDIM * H_DIM;
    _Float16* sg_b = down_b + (size_t)NE * H_DIM * IDIM;
    _Float16* su_b = sg_b + (size_t)SIDIM * H_DIM;
    _Float16* sd_b = su_b + (size_t)SIDIM * H_DIM;
    _Float16* hm = sd_b + (size_t)H_DIM * SIDIM;
    _Float16* hs = hm + (size_t)NE * NTOK * IDIM;
    float* wbuf = (float*)(hs + (size_t)NTOK * SIDIM);
    float* swbuf = wbuf + NTOK * NE;
    int* cnt = (int*)(swbuf + NTOK);
    int* list = cnt + 16;
    int* t128 = list + NE * NTOK;
    int* t64 = t128 + 64;

    dim3 blk(256);
    cvt_all_kernel<<<22144, blk, 0, stream>>>(x, egu, edown, sgw, suw, sdw,
                                              xb, gu_b, down_b, sg_b, su_b, sd_b);
    router_kernel<<<NTOK / 4, blk, 0, stream>>>(x, gate_w, segw, wbuf, swbuf);
    build_lists_kernel<<<1, 512, 0, stream>>>(wbuf, list, cnt, t128, t64);
    gemm1_kernel<0><<<dim3(40, IDIM / 64), blk, 0, stream>>>(
        xb, gu_b, nullptr, wbuf, list, cnt, t128, hm);
    gemm1_kernel<1><<<dim3(NTOK / 128, SIDIM / 64), blk, 0, stream>>>(
        xb, sg_b, su_b, swbuf, list, cnt, t128, hs);
    gemm2_kernel<1><<<dim3(NTOK / 64, H_DIM / 128), blk, 0, stream>>>(
        hs, sd_b, list, cnt, t64, out);
    gemm2_kernel<0><<<dim3(72, H_DIM / 128), blk, 0, stream>>>(
        hm, down_b, list, cnt, t64, out);
    (void)in_sizes; (void)n_in; (void)out_size; (void)ws_size;
}